// Round 9
// baseline (127.956 us; speedup 1.0000x reference)
//
#include <hip/hip_runtime.h>
#include <stdint.h>

typedef __bf16 bf16x4 __attribute__((ext_vector_type(4)));
typedef __bf16 bf16x8 __attribute__((ext_vector_type(8)));
typedef float  f32x4  __attribute__((ext_vector_type(4)));

#define HID 1024
#define SEQ 2048
#define NB  8

// ---------------------------------------------------------------------------
// prep_w: convert 3x(64x1024) fp32 weight mats to bf16 (one-time, ~0.4 MB)
// ---------------------------------------------------------------------------
__global__ __launch_bounds__(256) void prep_w(
    const float* __restrict__ Wq, const float* __restrict__ Wk,
    const float* __restrict__ Wv, __bf16* __restrict__ Wb)
{
    const int i = blockIdx.x * 256 + threadIdx.x;     // 49152 float4s total
    const int mat = i >> 14;                          // / 16384
    const int j   = i & 16383;
    const float* src = ((mat == 0) ? Wq : (mat == 1) ? Wk : Wv) + j * 4;
    float4 f = *(const float4*)src;
    bf16x4 o = { (__bf16)f.x, (__bf16)f.y, (__bf16)f.z, (__bf16)f.w };
    *(bf16x4*)(Wb + (size_t)i * 4) = o;
}

// ---------------------------------------------------------------------------
// Projection v9: copy-style streaming (m13 pattern — the 6.3 TB/s shape).
//   Block = 16 rows = one contiguous 64 KB slab. Thread t, instr j reads
//   slab + j*4KB + t*16B: per instruction = 4 KB contiguous (1 KB per wave).
//   Whole slab = block's total HBM demand: ONE burst of 16 loads/thread.
//   Slab -> bf16 -> LDS [16][1024] with 16B-unit XOR swizzle (u ^ ((row&7)<<1)).
//   4 waves split K (256 each): 8 MFMA steps, W frags from L2.
//   Partials (4 x 16x64 fp32) reduced via LDS aliased over dead X tile.
// q gets *0.125 folded in. v stored transposed vT[b][d][s].
// ---------------------------------------------------------------------------
__global__ __launch_bounds__(256) void proj_kernel(
    const float* __restrict__ Xq, const float* __restrict__ Xk, const float* __restrict__ Xv,
    const __bf16* __restrict__ Wb,
    const float* __restrict__ bq_, const float* __restrict__ bk_, const float* __restrict__ bv_,
    __bf16* __restrict__ qo, __bf16* __restrict__ ko, __bf16* __restrict__ vTo)
{
    const int mat = blockIdx.y;
    const float* X   = (mat == 0) ? Xq  : (mat == 1) ? Xk  : Xv;
    const __bf16* Wm = Wb + (size_t)mat * 64 * HID;
    const float* Bp  = (mat == 0) ? bq_ : (mat == 1) ? bk_ : bv_;

    const int row0 = blockIdx.x * 16;     // 16 rows per block
    const int tid  = threadIdx.x;
    const int lane = tid & 63;
    const int wv   = tid >> 6;            // wave 0..3 -> k-quarter
    const int lr   = lane & 15;
    const int g    = lane >> 4;           // 0..3

    __shared__ __align__(16) char smem[32768];
    __bf16* Xs = (__bf16*)smem;           // [16][1024] bf16, swizzled
    float*  Ps = (float*)smem;            // aliased partials [4][16][64] (16 KB)

    // ---- 1) stream the slab: 16 contiguous wave-instructions ----
    const float* slab = X + (size_t)row0 * HID;
    float4 xr[16];
    #pragma unroll
    for (int j = 0; j < 16; ++j)
        xr[j] = *(const float4*)(slab + j * 1024 + tid * 4);

    // ---- 2) convert + swizzled LDS write (row j, logical granule t) ----
    #pragma unroll
    for (int j = 0; j < 16; ++j) {
        const int u    = tid >> 1;                    // logical 16B unit 0..127
        const int phys = u ^ ((j & 7) << 1);
        const int gr   = phys * 2 + (tid & 1);        // physical 8B granule
        bf16x4 v = { (__bf16)xr[j].x, (__bf16)xr[j].y, (__bf16)xr[j].z, (__bf16)xr[j].w };
        *(bf16x4*)&Xs[j * 1024 + gr * 4] = v;
    }
    __syncthreads();

    // ---- 3) K-split MFMA: wave wv covers k in [wv*256, wv*256+256) ----
    f32x4 acc[4] = {};
    const int kq = wv * 256;
    #pragma unroll
    for (int s = 0; s < 8; ++s) {
        const int k0 = kq + s * 32;
        const int ul = (k0 >> 3) + g;                 // logical unit of A-frag
        bf16x8 af = *(const bf16x8*)&Xs[lr * 1024 + (ul ^ ((lr & 7) << 1)) * 8];
        #pragma unroll
        for (int ct = 0; ct < 4; ++ct) {
            bf16x8 bf = *(const bf16x8*)(Wm + (size_t)(ct * 16 + lr) * HID + k0 + 8 * g);
            acc[ct] = __builtin_amdgcn_mfma_f32_16x16x32_bf16(af, bf, acc[ct], 0, 0, 0);
        }
    }
    __syncthreads();                      // all reads of Xs done -> alias as Ps

    // ---- 4) write partials: Ps[(wv*16 + 4g+rr)*64 + ct*16+lr] ----
    #pragma unroll
    for (int ct = 0; ct < 4; ++ct)
        #pragma unroll
        for (int rr = 0; rr < 4; ++rr)
            Ps[(wv * 16 + 4 * g + rr) * 64 + ct * 16 + lr] = acc[ct][rr];
    __syncthreads();

    // ---- 5) reduce 4 partials + bias/scale, write output ----
    const float scl = (mat == 0) ? 0.125f : 1.0f;
    if (mat < 2) {
        __bf16* o = (mat == 0) ? qo : ko;
        // thread t: row = t>>4, d-group = (t&15)*4 -> one 8B write
        const int row = tid >> 4;
        const int dq  = (tid & 15) * 4;
        float v4[4];
        #pragma unroll
        for (int q = 0; q < 4; ++q) {
            const int d = dq + q;
            float s = Ps[(0 + row) * 64 + d] + Ps[(16 + row) * 64 + d]
                    + Ps[(32 + row) * 64 + d] + Ps[(48 + row) * 64 + d];
            v4[q] = (s + Bp[d]) * scl;
        }
        bf16x4 ov = { (__bf16)v4[0], (__bf16)v4[1], (__bf16)v4[2], (__bf16)v4[3] };
        *(bf16x4*)&o[(size_t)(row0 + row) * 64 + dq] = ov;
    } else {
        // v transpose: thread t: d = t>>2, srows (t&3)*4.. -> one 8B write
        const int d  = tid >> 2;
        const int sq = (tid & 3) * 4;
        const int b  = row0 >> 11;
        const int s0 = row0 & 2047;
        float v4[4];
        #pragma unroll
        for (int q = 0; q < 4; ++q) {
            const int row = sq + q;
            float s = Ps[(0 + row) * 64 + d] + Ps[(16 + row) * 64 + d]
                    + Ps[(32 + row) * 64 + d] + Ps[(48 + row) * 64 + d];
            v4[q] = s + Bp[d];
        }
        bf16x4 ov = { (__bf16)v4[0], (__bf16)v4[1], (__bf16)v4[2], (__bf16)v4[3] };
        *(bf16x4*)&vTo[((size_t)b * 64 + d) * SEQ + s0 + sq] = ov;
    }
}

// ---------------------------------------------------------------------------
// Flash attention with additive bias + key mask (unchanged — passed, ~4 TB/s).
// 128 thr (2 waves x 16 q-rows = 32 q-rows/block), 512 blocks.
// Register-prefetch of next K/V tile + bias/mask one iteration ahead.
// ---------------------------------------------------------------------------
__global__ __launch_bounds__(128) void attn_kernel(
    const __bf16* __restrict__ qws, const __bf16* __restrict__ kws,
    const __bf16* __restrict__ vTws, const float* __restrict__ bias,
    const int* __restrict__ mask, float* __restrict__ out)
{
    const int bid = blockIdx.x;
    const int b   = bid & 7;            // batch -> XCD round-robin (K/V L2 locality)
    const int q0  = (bid >> 3) * 32;
    const int tid = threadIdx.x;
    const int lane = tid & 63;
    const int wv   = tid >> 6;          // 0..1
    const int lr   = lane & 15;
    const int g    = lane >> 4;

    __shared__ __align__(16) __bf16 Kl[64 * 72];
    __shared__ __align__(16) __bf16 Vl[64 * 72];

    const int qrow = q0 + wv * 16 + lr;

    bf16x8 qf[2];
    {
        const __bf16* qp = qws + (size_t)(b * SEQ + qrow) * 64;
        #pragma unroll
        for (int dt = 0; dt < 2; ++dt) {
            bf16x4 lo = *(const bf16x4*)(qp + dt * 32 + 4 * g);
            bf16x4 hi = *(const bf16x4*)(qp + dt * 32 + 16 + 4 * g);
            qf[dt] = __builtin_shufflevector(lo, hi, 0, 1, 2, 3, 4, 5, 6, 7);
        }
    }

    f32x4 O[4] = {};
    float m   = -3.0e38f;
    float ell = 0.0f;

    const float* brow = bias + (size_t)(b * SEQ + qrow) * SEQ;
    const int*   mrow = mask + b * SEQ;

    const int sr = tid >> 1;            // staging row 0..63
    const int sc = (tid & 1) * 32;      // 32 elems = 4x bf16x8 per thread
    const __bf16* kbase = kws  + (size_t)(b * SEQ + sr) * 64 + sc;
    const __bf16* vbase = vTws + ((size_t)b * 64 + sr) * SEQ + sc;

    bf16x8 kr[4], vr[4];
    float4 bvn[4]; int4 mkn[4];

    auto loadt = [&](int kt) {
        const __bf16* ks = kbase + (size_t)kt * 64;
        kr[0] = *(const bf16x8*)ks;
        kr[1] = *(const bf16x8*)(ks + 8);
        kr[2] = *(const bf16x8*)(ks + 16);
        kr[3] = *(const bf16x8*)(ks + 24);
        const __bf16* vs = vbase + kt;
        vr[0] = *(const bf16x8*)vs;
        vr[1] = *(const bf16x8*)(vs + 8);
        vr[2] = *(const bf16x8*)(vs + 16);
        vr[3] = *(const bf16x8*)(vs + 24);
        #pragma unroll
        for (int s2t = 0; s2t < 4; ++s2t) {
            bvn[s2t] = *(const float4*)(brow + kt + s2t * 16 + 4 * g);
            mkn[s2t] = *(const int4*)(mrow + kt + s2t * 16 + 4 * g);
        }
    };

    loadt(0);

    #pragma unroll 2
    for (int kt = 0; kt < SEQ; kt += 64) {
        *(bf16x8*)&Kl[sr * 72 + sc]      = kr[0];
        *(bf16x8*)&Kl[sr * 72 + sc + 8]  = kr[1];
        *(bf16x8*)&Kl[sr * 72 + sc + 16] = kr[2];
        *(bf16x8*)&Kl[sr * 72 + sc + 24] = kr[3];
        *(bf16x8*)&Vl[sr * 72 + sc]      = vr[0];
        *(bf16x8*)&Vl[sr * 72 + sc + 8]  = vr[1];
        *(bf16x8*)&Vl[sr * 72 + sc + 16] = vr[2];
        *(bf16x8*)&Vl[sr * 72 + sc + 24] = vr[3];
        float4 bv4[4]; int4 mk4[4];
        #pragma unroll
        for (int s2t = 0; s2t < 4; ++s2t) { bv4[s2t] = bvn[s2t]; mk4[s2t] = mkn[s2t]; }
        __syncthreads();

        if (kt + 64 < SEQ) loadt(kt + 64);

        float p[16];
        #pragma unroll
        for (int s2t = 0; s2t < 4; ++s2t) {
            const int s2 = s2t * 16;
            f32x4 acc = {};
            #pragma unroll
            for (int dt = 0; dt < 2; ++dt) {
                bf16x4 klo = *(const bf16x4*)&Kl[(s2 + lr) * 72 + dt * 32 + 4 * g];
                bf16x4 khi = *(const bf16x4*)&Kl[(s2 + lr) * 72 + dt * 32 + 16 + 4 * g];
                bf16x8 kf = __builtin_shufflevector(klo, khi, 0, 1, 2, 3, 4, 5, 6, 7);
                acc = __builtin_amdgcn_mfma_f32_16x16x32_bf16(kf, qf[dt], acc, 0, 0, 0);
            }
            p[s2t * 4 + 0] = mk4[s2t].x ? acc[0] + 0.125f * bv4[s2t].x : -1e30f;
            p[s2t * 4 + 1] = mk4[s2t].y ? acc[1] + 0.125f * bv4[s2t].y : -1e30f;
            p[s2t * 4 + 2] = mk4[s2t].z ? acc[2] + 0.125f * bv4[s2t].z : -1e30f;
            p[s2t * 4 + 3] = mk4[s2t].w ? acc[3] + 0.125f * bv4[s2t].w : -1e30f;
        }

        float tmax = p[0];
        #pragma unroll
        for (int i = 1; i < 16; ++i) tmax = fmaxf(tmax, p[i]);
        tmax = fmaxf(tmax, __shfl_xor(tmax, 16));
        tmax = fmaxf(tmax, __shfl_xor(tmax, 32));
        const float mnew  = fmaxf(m, tmax);
        const float scale = __expf(m - mnew);
        m = mnew;
        float ssum = 0.0f;
        #pragma unroll
        for (int i = 0; i < 16; ++i) { p[i] = __expf(p[i] - mnew); ssum += p[i]; }
        ssum += __shfl_xor(ssum, 16);
        ssum += __shfl_xor(ssum, 32);
        ell = ell * scale + ssum;

        float scr[4];
        #pragma unroll
        for (int rr = 0; rr < 4; ++rr) scr[rr] = __shfl(scale, 4 * g + rr);
        #pragma unroll
        for (int t = 0; t < 4; ++t)
            #pragma unroll
            for (int rr = 0; rr < 4; ++rr) O[t][rr] *= scr[rr];

        bf16x8 pf0 = { (__bf16)p[0],  (__bf16)p[1],  (__bf16)p[2],  (__bf16)p[3],
                       (__bf16)p[4],  (__bf16)p[5],  (__bf16)p[6],  (__bf16)p[7] };
        bf16x8 pf1 = { (__bf16)p[8],  (__bf16)p[9],  (__bf16)p[10], (__bf16)p[11],
                       (__bf16)p[12], (__bf16)p[13], (__bf16)p[14], (__bf16)p[15] };

        #pragma unroll
        for (int t = 0; t < 4; ++t) {
            const int dr = (t * 16 + lr) * 72;
            bf16x4 v0lo = *(const bf16x4*)&Vl[dr + 4 * g];
            bf16x4 v0hi = *(const bf16x4*)&Vl[dr + 16 + 4 * g];
            bf16x8 vf0 = __builtin_shufflevector(v0lo, v0hi, 0, 1, 2, 3, 4, 5, 6, 7);
            O[t] = __builtin_amdgcn_mfma_f32_16x16x32_bf16(pf0, vf0, O[t], 0, 0, 0);
            bf16x4 v1lo = *(const bf16x4*)&Vl[dr + 32 + 4 * g];
            bf16x4 v1hi = *(const bf16x4*)&Vl[dr + 48 + 4 * g];
            bf16x8 vf1 = __builtin_shufflevector(v1lo, v1hi, 0, 1, 2, 3, 4, 5, 6, 7);
            O[t] = __builtin_amdgcn_mfma_f32_16x16x32_bf16(pf1, vf1, O[t], 0, 0, 0);
        }
        __syncthreads();
    }

    float linv[4];
    #pragma unroll
    for (int rr = 0; rr < 4; ++rr) linv[rr] = 1.0f / __shfl(ell, 4 * g + rr);

    float* orow = out + (size_t)(b * SEQ + q0 + wv * 16) * 64;
    #pragma unroll
    for (int t = 0; t < 4; ++t)
        #pragma unroll
        for (int rr = 0; rr < 4; ++rr)
            orow[(size_t)(4 * g + rr) * 64 + t * 16 + lr] = O[t][rr] * linv[rr];
}

extern "C" void kernel_launch(void* const* d_in, const int* in_sizes, int n_in,
                              void* d_out, int out_size, void* d_ws, size_t ws_size,
                              hipStream_t stream) {
    const float* query = (const float*)d_in[0];
    const float* key_  = (const float*)d_in[1];
    const float* value = (const float*)d_in[2];
    const float* rb    = (const float*)d_in[3];
    const int*   mask  = (const int*)d_in[4];
    const float* Wq = (const float*)d_in[5];
    const float* bq = (const float*)d_in[6];
    const float* Wk = (const float*)d_in[7];
    const float* bk = (const float*)d_in[8];
    const float* Wv = (const float*)d_in[9];
    const float* bv = (const float*)d_in[10];

    __bf16* qws = (__bf16*)d_ws;                       // [16384][64]
    __bf16* kws = qws + (size_t)16384 * 64;            // [16384][64]
    __bf16* vT  = kws + (size_t)16384 * 64;            // [8][64][2048]
    __bf16* Wbf = vT  + (size_t)8 * 64 * SEQ;          // [3][64][1024] bf16

    hipLaunchKernelGGL(prep_w, dim3(192), dim3(256), 0, stream, Wq, Wk, Wv, Wbf);
    hipLaunchKernelGGL(proj_kernel, dim3(1024, 3), dim3(256), 0, stream,
                       query, key_, value, Wbf, bq, bk, bv, qws, kws, vT);
    hipLaunchKernelGGL(attn_kernel, dim3(512), dim3(128), 0, stream,
                       qws, kws, vT, rb, mask, (float*)d_out);
}

// Round 10
// 127.738 us; speedup vs baseline: 1.0017x; 1.0017x over previous
//
#include <hip/hip_runtime.h>
#include <stdint.h>

typedef __bf16 bf16x4 __attribute__((ext_vector_type(4)));
typedef __bf16 bf16x8 __attribute__((ext_vector_type(8)));
typedef float  f32x4  __attribute__((ext_vector_type(4)));

#define HID 1024
#define SEQ 2048
#define NB  8

// ---------------------------------------------------------------------------
// prep_w: convert 3x(64x1024) fp32 weight mats to bf16 (one-time, ~0.4 MB)
// ---------------------------------------------------------------------------
__global__ __launch_bounds__(256) void prep_w(
    const float* __restrict__ Wq, const float* __restrict__ Wk,
    const float* __restrict__ Wv, __bf16* __restrict__ Wb)
{
    const int i = blockIdx.x * 256 + threadIdx.x;     // 49152 float4s total
    const int mat = i >> 14;                          // / 16384
    const int j   = i & 16383;
    const float* src = ((mat == 0) ? Wq : (mat == 1) ? Wk : Wv) + j * 4;
    float4 f = *(const float4*)src;
    bf16x4 o = { (__bf16)f.x, (__bf16)f.y, (__bf16)f.z, (__bf16)f.w };
    *(bf16x4*)(Wb + (size_t)i * 4) = o;
}

// ---------------------------------------------------------------------------
// Projection v10: R9 geometry, but the slab burst is FORCED via inline asm.
//   16 x global_load_dwordx4 into NAMED f32x4 regs -> compiler cannot sink
//   or recycle them; all 16 loads (16 KB/wave) are in flight simultaneously.
//   One s_waitcnt vmcnt(0) + sched_barrier(0) (rule #18) gates the convert.
//   Everything else identical to R9 (which passed):
//   slab -> bf16 -> LDS [16][1024] XOR-swizzled; 4 waves K-split MFMA;
//   partials reduced via LDS alias; bias/scale/v-transpose epilogue.
// q gets *0.125 folded in. v stored transposed vT[b][d][s].
// ---------------------------------------------------------------------------
__global__ __launch_bounds__(256) void proj_kernel(
    const float* __restrict__ Xq, const float* __restrict__ Xk, const float* __restrict__ Xv,
    const __bf16* __restrict__ Wb,
    const float* __restrict__ bq_, const float* __restrict__ bk_, const float* __restrict__ bv_,
    __bf16* __restrict__ qo, __bf16* __restrict__ ko, __bf16* __restrict__ vTo)
{
    const int mat = blockIdx.y;
    const float* X   = (mat == 0) ? Xq  : (mat == 1) ? Xk  : Xv;
    const __bf16* Wm = Wb + (size_t)mat * 64 * HID;
    const float* Bp  = (mat == 0) ? bq_ : (mat == 1) ? bk_ : bv_;

    const int row0 = blockIdx.x * 16;     // 16 rows per block
    const int tid  = threadIdx.x;
    const int lane = tid & 63;
    const int wv   = tid >> 6;            // wave 0..3 -> k-quarter
    const int lr   = lane & 15;
    const int g    = lane >> 4;           // 0..3

    __shared__ __align__(16) char smem[32768];
    __bf16* Xs = (__bf16*)smem;           // [16][1024] bf16, swizzled
    float*  Ps = (float*)smem;            // aliased partials [4][16][64] (16 KB)

    // ---- 1) stream the slab: 16 asm loads, ALL outstanding at once ----
    const float* base = X + (size_t)row0 * HID + tid * 4;   // +j*4096B per row
    f32x4 x0,x1,x2,x3,x4,x5,x6,x7,x8,x9,x10,x11,x12,x13,x14,x15;
    #define LDR(reg, j) \
        asm volatile("global_load_dwordx4 %0, %1, off" : "=v"(reg) : "v"(base + (j) * 1024))
    LDR(x0, 0);  LDR(x1, 1);  LDR(x2, 2);  LDR(x3, 3);
    LDR(x4, 4);  LDR(x5, 5);  LDR(x6, 6);  LDR(x7, 7);
    LDR(x8, 8);  LDR(x9, 9);  LDR(x10,10); LDR(x11,11);
    LDR(x12,12); LDR(x13,13); LDR(x14,14); LDR(x15,15);
    #undef LDR
    asm volatile("s_waitcnt vmcnt(0)" ::: "memory");
    __builtin_amdgcn_sched_barrier(0);

    // ---- 2) convert + swizzled LDS write (row j, logical granule tid) ----
    const int u_  = tid >> 1;                     // logical 16B unit 0..127
    const int gpar = tid & 1;
    #define WRX(reg, j) do {                                                   \
        const int phys = u_ ^ (((j) & 7) << 1);                                \
        bf16x4 v = { (__bf16)(reg).x, (__bf16)(reg).y,                         \
                     (__bf16)(reg).z, (__bf16)(reg).w };                       \
        *(bf16x4*)&Xs[(j) * 1024 + (phys * 2 + gpar) * 4] = v;                 \
    } while (0)
    WRX(x0, 0);  WRX(x1, 1);  WRX(x2, 2);  WRX(x3, 3);
    WRX(x4, 4);  WRX(x5, 5);  WRX(x6, 6);  WRX(x7, 7);
    WRX(x8, 8);  WRX(x9, 9);  WRX(x10,10); WRX(x11,11);
    WRX(x12,12); WRX(x13,13); WRX(x14,14); WRX(x15,15);
    #undef WRX
    __syncthreads();

    // ---- 3) K-split MFMA: wave wv covers k in [wv*256, wv*256+256) ----
    f32x4 acc[4] = {};
    const int kq = wv * 256;
    #pragma unroll
    for (int s = 0; s < 8; ++s) {
        const int k0 = kq + s * 32;
        const int ul = (k0 >> 3) + g;                 // logical unit of A-frag
        bf16x8 af = *(const bf16x8*)&Xs[lr * 1024 + (ul ^ ((lr & 7) << 1)) * 8];
        #pragma unroll
        for (int ct = 0; ct < 4; ++ct) {
            bf16x8 bf = *(const bf16x8*)(Wm + (size_t)(ct * 16 + lr) * HID + k0 + 8 * g);
            acc[ct] = __builtin_amdgcn_mfma_f32_16x16x32_bf16(af, bf, acc[ct], 0, 0, 0);
        }
    }
    __syncthreads();                      // all reads of Xs done -> alias as Ps

    // ---- 4) write partials: Ps[(wv*16 + 4g+rr)*64 + ct*16+lr] ----
    #pragma unroll
    for (int ct = 0; ct < 4; ++ct)
        #pragma unroll
        for (int rr = 0; rr < 4; ++rr)
            Ps[(wv * 16 + 4 * g + rr) * 64 + ct * 16 + lr] = acc[ct][rr];
    __syncthreads();

    // ---- 5) reduce 4 partials + bias/scale, write output ----
    const float scl = (mat == 0) ? 0.125f : 1.0f;
    if (mat < 2) {
        __bf16* o = (mat == 0) ? qo : ko;
        const int row = tid >> 4;
        const int dq  = (tid & 15) * 4;
        float v4[4];
        #pragma unroll
        for (int q = 0; q < 4; ++q) {
            const int d = dq + q;
            float s = Ps[(0 + row) * 64 + d] + Ps[(16 + row) * 64 + d]
                    + Ps[(32 + row) * 64 + d] + Ps[(48 + row) * 64 + d];
            v4[q] = (s + Bp[d]) * scl;
        }
        bf16x4 ov = { (__bf16)v4[0], (__bf16)v4[1], (__bf16)v4[2], (__bf16)v4[3] };
        *(bf16x4*)&o[(size_t)(row0 + row) * 64 + dq] = ov;
    } else {
        const int d  = tid >> 2;
        const int sq = (tid & 3) * 4;
        const int b  = row0 >> 11;
        const int s0 = row0 & 2047;
        float v4[4];
        #pragma unroll
        for (int q = 0; q < 4; ++q) {
            const int row = sq + q;
            float s = Ps[(0 + row) * 64 + d] + Ps[(16 + row) * 64 + d]
                    + Ps[(32 + row) * 64 + d] + Ps[(48 + row) * 64 + d];
            v4[q] = s + Bp[d];
        }
        bf16x4 ov = { (__bf16)v4[0], (__bf16)v4[1], (__bf16)v4[2], (__bf16)v4[3] };
        *(bf16x4*)&vTo[((size_t)b * 64 + d) * SEQ + s0 + sq] = ov;
    }
}

// ---------------------------------------------------------------------------
// Flash attention with additive bias + key mask (unchanged — passed, fast).
// 128 thr (2 waves x 16 q-rows = 32 q-rows/block), 512 blocks.
// Register-prefetch of next K/V tile + bias/mask one iteration ahead.
// ---------------------------------------------------------------------------
__global__ __launch_bounds__(128) void attn_kernel(
    const __bf16* __restrict__ qws, const __bf16* __restrict__ kws,
    const __bf16* __restrict__ vTws, const float* __restrict__ bias,
    const int* __restrict__ mask, float* __restrict__ out)
{
    const int bid = blockIdx.x;
    const int b   = bid & 7;            // batch -> XCD round-robin (K/V L2 locality)
    const int q0  = (bid >> 3) * 32;
    const int tid = threadIdx.x;
    const int lane = tid & 63;
    const int wv   = tid >> 6;          // 0..1
    const int lr   = lane & 15;
    const int g    = lane >> 4;

    __shared__ __align__(16) __bf16 Kl[64 * 72];
    __shared__ __align__(16) __bf16 Vl[64 * 72];

    const int qrow = q0 + wv * 16 + lr;

    bf16x8 qf[2];
    {
        const __bf16* qp = qws + (size_t)(b * SEQ + qrow) * 64;
        #pragma unroll
        for (int dt = 0; dt < 2; ++dt) {
            bf16x4 lo = *(const bf16x4*)(qp + dt * 32 + 4 * g);
            bf16x4 hi = *(const bf16x4*)(qp + dt * 32 + 16 + 4 * g);
            qf[dt] = __builtin_shufflevector(lo, hi, 0, 1, 2, 3, 4, 5, 6, 7);
        }
    }

    f32x4 O[4] = {};
    float m   = -3.0e38f;
    float ell = 0.0f;

    const float* brow = bias + (size_t)(b * SEQ + qrow) * SEQ;
    const int*   mrow = mask + b * SEQ;

    const int sr = tid >> 1;            // staging row 0..63
    const int sc = (tid & 1) * 32;      // 32 elems = 4x bf16x8 per thread
    const __bf16* kbase = kws  + (size_t)(b * SEQ + sr) * 64 + sc;
    const __bf16* vbase = vTws + ((size_t)b * 64 + sr) * SEQ + sc;

    bf16x8 kr[4], vr[4];
    float4 bvn[4]; int4 mkn[4];

    auto loadt = [&](int kt) {
        const __bf16* ks = kbase + (size_t)kt * 64;
        kr[0] = *(const bf16x8*)ks;
        kr[1] = *(const bf16x8*)(ks + 8);
        kr[2] = *(const bf16x8*)(ks + 16);
        kr[3] = *(const bf16x8*)(ks + 24);
        const __bf16* vs = vbase + kt;
        vr[0] = *(const bf16x8*)vs;
        vr[1] = *(const bf16x8*)(vs + 8);
        vr[2] = *(const bf16x8*)(vs + 16);
        vr[3] = *(const bf16x8*)(vs + 24);
        #pragma unroll
        for (int s2t = 0; s2t < 4; ++s2t) {
            bvn[s2t] = *(const float4*)(brow + kt + s2t * 16 + 4 * g);
            mkn[s2t] = *(const int4*)(mrow + kt + s2t * 16 + 4 * g);
        }
    };

    loadt(0);

    #pragma unroll 2
    for (int kt = 0; kt < SEQ; kt += 64) {
        *(bf16x8*)&Kl[sr * 72 + sc]      = kr[0];
        *(bf16x8*)&Kl[sr * 72 + sc + 8]  = kr[1];
        *(bf16x8*)&Kl[sr * 72 + sc + 16] = kr[2];
        *(bf16x8*)&Kl[sr * 72 + sc + 24] = kr[3];
        *(bf16x8*)&Vl[sr * 72 + sc]      = vr[0];
        *(bf16x8*)&Vl[sr * 72 + sc + 8]  = vr[1];
        *(bf16x8*)&Vl[sr * 72 + sc + 16] = vr[2];
        *(bf16x8*)&Vl[sr * 72 + sc + 24] = vr[3];
        float4 bv4[4]; int4 mk4[4];
        #pragma unroll
        for (int s2t = 0; s2t < 4; ++s2t) { bv4[s2t] = bvn[s2t]; mk4[s2t] = mkn[s2t]; }
        __syncthreads();

        if (kt + 64 < SEQ) loadt(kt + 64);

        float p[16];
        #pragma unroll
        for (int s2t = 0; s2t < 4; ++s2t) {
            const int s2 = s2t * 16;
            f32x4 acc = {};
            #pragma unroll
            for (int dt = 0; dt < 2; ++dt) {
                bf16x4 klo = *(const bf16x4*)&Kl[(s2 + lr) * 72 + dt * 32 + 4 * g];
                bf16x4 khi = *(const bf16x4*)&Kl[(s2 + lr) * 72 + dt * 32 + 16 + 4 * g];
                bf16x8 kf = __builtin_shufflevector(klo, khi, 0, 1, 2, 3, 4, 5, 6, 7);
                acc = __builtin_amdgcn_mfma_f32_16x16x32_bf16(kf, qf[dt], acc, 0, 0, 0);
            }
            p[s2t * 4 + 0] = mk4[s2t].x ? acc[0] + 0.125f * bv4[s2t].x : -1e30f;
            p[s2t * 4 + 1] = mk4[s2t].y ? acc[1] + 0.125f * bv4[s2t].y : -1e30f;
            p[s2t * 4 + 2] = mk4[s2t].z ? acc[2] + 0.125f * bv4[s2t].z : -1e30f;
            p[s2t * 4 + 3] = mk4[s2t].w ? acc[3] + 0.125f * bv4[s2t].w : -1e30f;
        }

        float tmax = p[0];
        #pragma unroll
        for (int i = 1; i < 16; ++i) tmax = fmaxf(tmax, p[i]);
        tmax = fmaxf(tmax, __shfl_xor(tmax, 16));
        tmax = fmaxf(tmax, __shfl_xor(tmax, 32));
        const float mnew  = fmaxf(m, tmax);
        const float scale = __expf(m - mnew);
        m = mnew;
        float ssum = 0.0f;
        #pragma unroll
        for (int i = 0; i < 16; ++i) { p[i] = __expf(p[i] - mnew); ssum += p[i]; }
        ssum += __shfl_xor(ssum, 16);
        ssum += __shfl_xor(ssum, 32);
        ell = ell * scale + ssum;

        float scr[4];
        #pragma unroll
        for (int rr = 0; rr < 4; ++rr) scr[rr] = __shfl(scale, 4 * g + rr);
        #pragma unroll
        for (int t = 0; t < 4; ++t)
            #pragma unroll
            for (int rr = 0; rr < 4; ++rr) O[t][rr] *= scr[rr];

        bf16x8 pf0 = { (__bf16)p[0],  (__bf16)p[1],  (__bf16)p[2],  (__bf16)p[3],
                       (__bf16)p[4],  (__bf16)p[5],  (__bf16)p[6],  (__bf16)p[7] };
        bf16x8 pf1 = { (__bf16)p[8],  (__bf16)p[9],  (__bf16)p[10], (__bf16)p[11],
                       (__bf16)p[12], (__bf16)p[13], (__bf16)p[14], (__bf16)p[15] };

        #pragma unroll
        for (int t = 0; t < 4; ++t) {
            const int dr = (t * 16 + lr) * 72;
            bf16x4 v0lo = *(const bf16x4*)&Vl[dr + 4 * g];
            bf16x4 v0hi = *(const bf16x4*)&Vl[dr + 16 + 4 * g];
            bf16x8 vf0 = __builtin_shufflevector(v0lo, v0hi, 0, 1, 2, 3, 4, 5, 6, 7);
            O[t] = __builtin_amdgcn_mfma_f32_16x16x32_bf16(pf0, vf0, O[t], 0, 0, 0);
            bf16x4 v1lo = *(const bf16x4*)&Vl[dr + 32 + 4 * g];
            bf16x4 v1hi = *(const bf16x4*)&Vl[dr + 48 + 4 * g];
            bf16x8 vf1 = __builtin_shufflevector(v1lo, v1hi, 0, 1, 2, 3, 4, 5, 6, 7);
            O[t] = __builtin_amdgcn_mfma_f32_16x16x32_bf16(pf1, vf1, O[t], 0, 0, 0);
        }
        __syncthreads();
    }

    float linv[4];
    #pragma unroll
    for (int rr = 0; rr < 4; ++rr) linv[rr] = 1.0f / __shfl(ell, 4 * g + rr);

    float* orow = out + (size_t)(b * SEQ + q0 + wv * 16) * 64;
    #pragma unroll
    for (int t = 0; t < 4; ++t)
        #pragma unroll
        for (int rr = 0; rr < 4; ++rr)
            orow[(size_t)(4 * g + rr) * 64 + t * 16 + lr] = O[t][rr] * linv[rr];
}

extern "C" void kernel_launch(void* const* d_in, const int* in_sizes, int n_in,
                              void* d_out, int out_size, void* d_ws, size_t ws_size,
                              hipStream_t stream) {
    const float* query = (const float*)d_in[0];
    const float* key_  = (const float*)d_in[1];
    const float* value = (const float*)d_in[2];
    const float* rb    = (const float*)d_in[3];
    const int*   mask  = (const int*)d_in[4];
    const float* Wq = (const float*)d_in[5];
    const float* bq = (const float*)d_in[6];
    const float* Wk = (const float*)d_in[7];
    const float* bk = (const float*)d_in[8];
    const float* Wv = (const float*)d_in[9];
    const float* bv = (const float*)d_in[10];

    __bf16* qws = (__bf16*)d_ws;                       // [16384][64]
    __bf16* kws = qws + (size_t)16384 * 64;            // [16384][64]
    __bf16* vT  = kws + (size_t)16384 * 64;            // [8][64][2048]
    __bf16* Wbf = vT  + (size_t)8 * 64 * SEQ;          // [3][64][1024] bf16

    hipLaunchKernelGGL(prep_w, dim3(192), dim3(256), 0, stream, Wq, Wk, Wv, Wbf);
    hipLaunchKernelGGL(proj_kernel, dim3(1024, 3), dim3(256), 0, stream,
                       query, key_, value, Wbf, bq, bk, bv, qws, kws, vT);
    hipLaunchKernelGGL(attn_kernel, dim3(512), dim3(128), 0, stream,
                       qws, kws, vT, rb, mask, (float*)d_out);
}

// Round 11
// 92.058 us; speedup vs baseline: 1.3900x; 1.3876x over previous
//
#include <hip/hip_runtime.h>
#include <stdint.h>

typedef __bf16 bf16x4 __attribute__((ext_vector_type(4)));
typedef __bf16 bf16x8 __attribute__((ext_vector_type(8)));
typedef float  f32x4  __attribute__((ext_vector_type(4)));

#define HID 1024
#define SEQ 2048
#define NB  8

// async global->LDS, 16 B per lane, wave-uniform LDS base.
// AUX: cache-policy bits (gfx94x/gfx950 CPol: SC0=1, NT=2, SC1=16).
template <int AUX>
__device__ __forceinline__ void gl_lds16(const void* g, void* l) {
    __builtin_amdgcn_global_load_lds(
        (const __attribute__((address_space(1))) void*)g,
        (__attribute__((address_space(3))) void*)l, 16, 0, AUX);
}

// ---------------------------------------------------------------------------
// prep_w: convert 3x(64x1024) fp32 weight mats to bf16 (one-time, ~0.4 MB)
// ---------------------------------------------------------------------------
__global__ __launch_bounds__(256) void prep_w(
    const float* __restrict__ Wq, const float* __restrict__ Wk,
    const float* __restrict__ Wv, __bf16* __restrict__ Wb)
{
    const int i = blockIdx.x * 256 + threadIdx.x;     // 49152 float4s total
    const int mat = i >> 14;                          // / 16384
    const int j   = i & 16383;
    const float* src = ((mat == 0) ? Wq : (mat == 1) ? Wk : Wv) + j * 4;
    float4 f = *(const float4*)src;
    bf16x4 o = { (__bf16)f.x, (__bf16)f.y, (__bf16)f.z, (__bf16)f.w };
    *(bf16x4*)(Wb + (size_t)i * 4) = o;
}

// ---------------------------------------------------------------------------
// Projection v11 = R5 (best measured: 78 us) with ONE change:
//   X staging loads are NON-TEMPORAL (NT) -> no L3 allocation for the 192 MB
//   one-shot X stream; bias/ws stay L3-resident; no allocate/evict churn.
// Structure (identical to R5): T3+T4 pipeline — raw s_barrier + COUNTED
// vmcnt (never 0 in loop). K-step 64. X (fp32) and W (bf16) double-buffered
// in LDS via global_load_lds with pre-swizzled sources (XOR involution):
//   X: row r, 16B-unit u at phys u^(r&7)   (16 units/row)
//   W: row d, 16B-unit u at phys u^(d&7)   ( 8 units/row)
// Per wave per k-step: 4 X + 2 W = 6 gload_lds. Schedule:
//   prologue: STAGE(0,buf0), STAGE(1,buf1)
//   iter t:   vmcnt(6|0) ; s_barrier ; compute buf[t&1] ; s_barrier ;
//             STAGE(t+2, buf[t&1])
// q gets *0.125 folded in. v stored transposed vT[b][d][s].
// ---------------------------------------------------------------------------
__global__ __launch_bounds__(256, 3) void proj_kernel(
    const float* __restrict__ Xq, const float* __restrict__ Xk, const float* __restrict__ Xv,
    const __bf16* __restrict__ Wb,
    const float* __restrict__ bq_, const float* __restrict__ bk_, const float* __restrict__ bv_,
    __bf16* __restrict__ qo, __bf16* __restrict__ ko, __bf16* __restrict__ vTo)
{
    const int mat = blockIdx.y;
    const float* X   = (mat == 0) ? Xq  : (mat == 1) ? Xk  : Xv;
    const __bf16* Wm = Wb + (size_t)mat * 64 * HID;
    const float* Bp  = (mat == 0) ? bq_ : (mat == 1) ? bk_ : bv_;

    const int row0 = blockIdx.x * 64;
    const int tid  = threadIdx.x;
    const int lane = tid & 63;
    const int wv   = tid >> 6;      // wave 0..3 -> rows wv*16..
    const int lr   = lane & 15;
    const int g    = lane >> 4;     // 0..3

    __shared__ __align__(16) float  Xl[2][64 * 64];   // 2 x 16 KB
    __shared__ __align__(16) __bf16 Wl[2][64 * 64];   // 2 x  8 KB

    f32x4 acc[4] = {};

    // ---- staging lambda: 6 gload_lds per wave, contiguous swizzled sources ----
    auto STAGE = [&](int t, int pb) {
        const int k0 = t * 64;
        #pragma unroll
        for (int j = 0; j < 4; ++j) {               // X: 4 rows per instr, NT
            const int row = wv * 16 + 4 * j + (lane >> 4);
            const int c   = row & 7;
            const float* src = X + (size_t)(row0 + row) * HID + k0 + 4 * ((lane & 15) ^ c);
            gl_lds16<2>(src, &Xl[pb][(wv * 16 + 4 * j) * 64]);
        }
        #pragma unroll
        for (int j = 0; j < 2; ++j) {               // W: 8 rows per instr, cached
            const int row = wv * 16 + 8 * j + (lane >> 3);
            const int c   = row & 7;
            const __bf16* src = Wm + (size_t)row * HID + k0 + 8 * ((lane & 7) ^ c);
            gl_lds16<0>(src, &Wl[pb][(wv * 16 + 8 * j) * 64]);
        }
    };

    STAGE(0, 0);
    STAGE(1, 1);

    const int r  = wv * 16 + lr;      // A-frag row
    const int cx = lr & 7;            // swizzle key (row&7 == lr&7 here)

    for (int t = 0; t < 16; ++t) {
        const int pb = t & 1;
        if (t < 15) { asm volatile("s_waitcnt vmcnt(6)" ::: "memory"); }
        else        { asm volatile("s_waitcnt vmcnt(0)" ::: "memory"); }
        __builtin_amdgcn_s_barrier();

        #pragma unroll
        for (int kk = 0; kk < 2; ++kk) {            // k-slice 0 / 32
            const int ulo = 2 * g + 8 * kk;
            f32x4 xa = *(const f32x4*)&Xl[pb][r * 64 + (((ulo)     ^ cx) << 2)];
            f32x4 xb = *(const f32x4*)&Xl[pb][r * 64 + (((ulo + 1) ^ cx) << 2)];
            bf16x8 af = { (__bf16)xa.x, (__bf16)xa.y, (__bf16)xa.z, (__bf16)xa.w,
                          (__bf16)xb.x, (__bf16)xb.y, (__bf16)xb.z, (__bf16)xb.w };
            #pragma unroll
            for (int ct = 0; ct < 4; ++ct) {
                const int uw = g + 4 * kk;
                bf16x8 bf = *(const bf16x8*)&Wl[pb][(ct * 16 + lr) * 64 + ((uw ^ cx) << 3)];
                acc[ct] = __builtin_amdgcn_mfma_f32_16x16x32_bf16(af, bf, acc[ct], 0, 0, 0);
            }
        }

        __builtin_amdgcn_s_barrier();
        if (t + 2 < 16) STAGE(t + 2, pb);
    }

    const float scl = (mat == 0) ? 0.125f : 1.0f;
    float res[4][4];
    #pragma unroll
    for (int ct = 0; ct < 4; ++ct) {
        const float bval = Bp[ct * 16 + lr];
        #pragma unroll
        for (int rr = 0; rr < 4; ++rr) res[ct][rr] = (acc[ct][rr] + bval) * scl;
    }

    if (mat < 2) {
        __bf16* o = (mat == 0) ? qo : ko;
        // D-layout: row = 4g+rr, col = ct*16+lr
        #pragma unroll
        for (int ct = 0; ct < 4; ++ct)
            #pragma unroll
            for (int rr = 0; rr < 4; ++rr)
                o[(size_t)(row0 + wv * 16 + 4 * g + rr) * 64 + ct * 16 + lr] = (__bf16)res[ct][rr];
    } else {
        // transpose v tile via LDS (alias Xl), write vT[b][d][s] coalesced
        __bf16* Tl = (__bf16*)&Xl[0][0];
        __syncthreads();
        #pragma unroll
        for (int ct = 0; ct < 4; ++ct)
            #pragma unroll
            for (int rr = 0; rr < 4; ++rr)
                Tl[(ct * 16 + lr) * 72 + wv * 16 + 4 * g + rr] = (__bf16)res[ct][rr];
        __syncthreads();
        const int d   = tid >> 2;
        const int sc_ = (tid & 3) * 16;
        const int b   = row0 >> 11;
        const int s0  = row0 & 2047;
        __bf16* dst = vTo + ((size_t)b * 64 + d) * SEQ + s0 + sc_;
        *(bf16x8*)dst       = *(const bf16x8*)&Tl[d * 72 + sc_];
        *(bf16x8*)(dst + 8) = *(const bf16x8*)&Tl[d * 72 + sc_ + 8];
    }
}

// ---------------------------------------------------------------------------
// Flash attention with additive bias + key mask (unchanged — passed, fast).
// 128 thr (2 waves x 16 q-rows = 32 q-rows/block), 512 blocks.
// Register-prefetch of next K/V tile + bias/mask one iteration ahead.
// ---------------------------------------------------------------------------
__global__ __launch_bounds__(128) void attn_kernel(
    const __bf16* __restrict__ qws, const __bf16* __restrict__ kws,
    const __bf16* __restrict__ vTws, const float* __restrict__ bias,
    const int* __restrict__ mask, float* __restrict__ out)
{
    const int bid = blockIdx.x;
    const int b   = bid & 7;            // batch -> XCD round-robin (K/V L2 locality)
    const int q0  = (bid >> 3) * 32;
    const int tid = threadIdx.x;
    const int lane = tid & 63;
    const int wv   = tid >> 6;          // 0..1
    const int lr   = lane & 15;
    const int g    = lane >> 4;

    __shared__ __align__(16) __bf16 Kl[64 * 72];
    __shared__ __align__(16) __bf16 Vl[64 * 72];

    const int qrow = q0 + wv * 16 + lr;

    bf16x8 qf[2];
    {
        const __bf16* qp = qws + (size_t)(b * SEQ + qrow) * 64;
        #pragma unroll
        for (int dt = 0; dt < 2; ++dt) {
            bf16x4 lo = *(const bf16x4*)(qp + dt * 32 + 4 * g);
            bf16x4 hi = *(const bf16x4*)(qp + dt * 32 + 16 + 4 * g);
            qf[dt] = __builtin_shufflevector(lo, hi, 0, 1, 2, 3, 4, 5, 6, 7);
        }
    }

    f32x4 O[4] = {};
    float m   = -3.0e38f;
    float ell = 0.0f;

    const float* brow = bias + (size_t)(b * SEQ + qrow) * SEQ;
    const int*   mrow = mask + b * SEQ;

    const int sr = tid >> 1;            // staging row 0..63
    const int sc = (tid & 1) * 32;      // 32 elems = 4x bf16x8 per thread
    const __bf16* kbase = kws  + (size_t)(b * SEQ + sr) * 64 + sc;
    const __bf16* vbase = vTws + ((size_t)b * 64 + sr) * SEQ + sc;

    bf16x8 kr[4], vr[4];
    float4 bvn[4]; int4 mkn[4];

    auto loadt = [&](int kt) {
        const __bf16* ks = kbase + (size_t)kt * 64;
        kr[0] = *(const bf16x8*)ks;
        kr[1] = *(const bf16x8*)(ks + 8);
        kr[2] = *(const bf16x8*)(ks + 16);
        kr[3] = *(const bf16x8*)(ks + 24);
        const __bf16* vs = vbase + kt;
        vr[0] = *(const bf16x8*)vs;
        vr[1] = *(const bf16x8*)(vs + 8);
        vr[2] = *(const bf16x8*)(vs + 16);
        vr[3] = *(const bf16x8*)(vs + 24);
        #pragma unroll
        for (int s2t = 0; s2t < 4; ++s2t) {
            bvn[s2t] = *(const float4*)(brow + kt + s2t * 16 + 4 * g);
            mkn[s2t] = *(const int4*)(mrow + kt + s2t * 16 + 4 * g);
        }
    };

    loadt(0);

    #pragma unroll 2
    for (int kt = 0; kt < SEQ; kt += 64) {
        *(bf16x8*)&Kl[sr * 72 + sc]      = kr[0];
        *(bf16x8*)&Kl[sr * 72 + sc + 8]  = kr[1];
        *(bf16x8*)&Kl[sr * 72 + sc + 16] = kr[2];
        *(bf16x8*)&Kl[sr * 72 + sc + 24] = kr[3];
        *(bf16x8*)&Vl[sr * 72 + sc]      = vr[0];
        *(bf16x8*)&Vl[sr * 72 + sc + 8]  = vr[1];
        *(bf16x8*)&Vl[sr * 72 + sc + 16] = vr[2];
        *(bf16x8*)&Vl[sr * 72 + sc + 24] = vr[3];
        float4 bv4[4]; int4 mk4[4];
        #pragma unroll
        for (int s2t = 0; s2t < 4; ++s2t) { bv4[s2t] = bvn[s2t]; mk4[s2t] = mkn[s2t]; }
        __syncthreads();

        if (kt + 64 < SEQ) loadt(kt + 64);

        float p[16];
        #pragma unroll
        for (int s2t = 0; s2t < 4; ++s2t) {
            const int s2 = s2t * 16;
            f32x4 acc = {};
            #pragma unroll
            for (int dt = 0; dt < 2; ++dt) {
                bf16x4 klo = *(const bf16x4*)&Kl[(s2 + lr) * 72 + dt * 32 + 4 * g];
                bf16x4 khi = *(const bf16x4*)&Kl[(s2 + lr) * 72 + dt * 32 + 16 + 4 * g];
                bf16x8 kf = __builtin_shufflevector(klo, khi, 0, 1, 2, 3, 4, 5, 6, 7);
                acc = __builtin_amdgcn_mfma_f32_16x16x32_bf16(kf, qf[dt], acc, 0, 0, 0);
            }
            p[s2t * 4 + 0] = mk4[s2t].x ? acc[0] + 0.125f * bv4[s2t].x : -1e30f;
            p[s2t * 4 + 1] = mk4[s2t].y ? acc[1] + 0.125f * bv4[s2t].y : -1e30f;
            p[s2t * 4 + 2] = mk4[s2t].z ? acc[2] + 0.125f * bv4[s2t].z : -1e30f;
            p[s2t * 4 + 3] = mk4[s2t].w ? acc[3] + 0.125f * bv4[s2t].w : -1e30f;
        }

        float tmax = p[0];
        #pragma unroll
        for (int i = 1; i < 16; ++i) tmax = fmaxf(tmax, p[i]);
        tmax = fmaxf(tmax, __shfl_xor(tmax, 16));
        tmax = fmaxf(tmax, __shfl_xor(tmax, 32));
        const float mnew  = fmaxf(m, tmax);
        const float scale = __expf(m - mnew);
        m = mnew;
        float ssum = 0.0f;
        #pragma unroll
        for (int i = 0; i < 16; ++i) { p[i] = __expf(p[i] - mnew); ssum += p[i]; }
        ssum += __shfl_xor(ssum, 16);
        ssum += __shfl_xor(ssum, 32);
        ell = ell * scale + ssum;

        float scr[4];
        #pragma unroll
        for (int rr = 0; rr < 4; ++rr) scr[rr] = __shfl(scale, 4 * g + rr);
        #pragma unroll
        for (int t = 0; t < 4; ++t)
            #pragma unroll
            for (int rr = 0; rr < 4; ++rr) O[t][rr] *= scr[rr];

        bf16x8 pf0 = { (__bf16)p[0],  (__bf16)p[1],  (__bf16)p[2],  (__bf16)p[3],
                       (__bf16)p[4],  (__bf16)p[5],  (__bf16)p[6],  (__bf16)p[7] };
        bf16x8 pf1 = { (__bf16)p[8],  (__bf16)p[9],  (__bf16)p[10], (__bf16)p[11],
                       (__bf16)p[12], (__bf16)p[13], (__bf16)p[14], (__bf16)p[15] };

        #pragma unroll
        for (int t = 0; t < 4; ++t) {
            const int dr = (t * 16 + lr) * 72;
            bf16x4 v0lo = *(const bf16x4*)&Vl[dr + 4 * g];
            bf16x4 v0hi = *(const bf16x4*)&Vl[dr + 16 + 4 * g];
            bf16x8 vf0 = __builtin_shufflevector(v0lo, v0hi, 0, 1, 2, 3, 4, 5, 6, 7);
            O[t] = __builtin_amdgcn_mfma_f32_16x16x32_bf16(pf0, vf0, O[t], 0, 0, 0);
            bf16x4 v1lo = *(const bf16x4*)&Vl[dr + 32 + 4 * g];
            bf16x4 v1hi = *(const bf16x4*)&Vl[dr + 48 + 4 * g];
            bf16x8 vf1 = __builtin_shufflevector(v1lo, v1hi, 0, 1, 2, 3, 4, 5, 6, 7);
            O[t] = __builtin_amdgcn_mfma_f32_16x16x32_bf16(pf1, vf1, O[t], 0, 0, 0);
        }
        __syncthreads();
    }

    float linv[4];
    #pragma unroll
    for (int rr = 0; rr < 4; ++rr) linv[rr] = 1.0f / __shfl(ell, 4 * g + rr);

    float* orow = out + (size_t)(b * SEQ + q0 + wv * 16) * 64;
    #pragma unroll
    for (int t = 0; t < 4; ++t)
        #pragma unroll
        for (int rr = 0; rr < 4; ++rr)
            orow[(size_t)(4 * g + rr) * 64 + t * 16 + lr] = O[t][rr] * linv[rr];
}

extern "C" void kernel_launch(void* const* d_in, const int* in_sizes, int n_in,
                              void* d_out, int out_size, void* d_ws, size_t ws_size,
                              hipStream_t stream) {
    const float* query = (const float*)d_in[0];
    const float* key_  = (const float*)d_in[1];
    const float* value = (const float*)d_in[2];
    const float* rb    = (const float*)d_in[3];
    const int*   mask  = (const int*)d_in[4];
    const float* Wq = (const float*)d_in[5];
    const float* bq = (const float*)d_in[6];
    const float* Wk = (const float*)d_in[7];
    const float* bk = (const float*)d_in[8];
    const float* Wv = (const float*)d_in[9];
    const float* bv = (const float*)d_in[10];

    __bf16* qws = (__bf16*)d_ws;                       // [16384][64]
    __bf16* kws = qws + (size_t)16384 * 64;            // [16384][64]
    __bf16* vT  = kws + (size_t)16384 * 64;            // [8][64][2048]
    __bf16* Wbf = vT  + (size_t)8 * 64 * SEQ;          // [3][64][1024] bf16

    hipLaunchKernelGGL(prep_w, dim3(192), dim3(256), 0, stream, Wq, Wk, Wv, Wbf);
    hipLaunchKernelGGL(proj_kernel, dim3(256, 3), dim3(256), 0, stream,
                       query, key_, value, Wbf, bq, bk, bv, qws, kws, vT);
    hipLaunchKernelGGL(attn_kernel, dim3(512), dim3(128), 0, stream,
                       qws, kws, vT, rb, mask, (float*)d_out);
}